// Round 4
// baseline (804.589 us; speedup 1.0000x reference)
//
#include <hip/hip_runtime.h>
#include <hip/hip_bf16.h>

#define B_ 2
#define N_ 8
#define C_ 64
#define H_ 192
#define W_ 256
#define V_ 200000
#define OUT_ 128
#define HW_ (H_*W_)        // 49152
#define R_ (N_*HW_)        // 393216
#define BV_ (B_*V_)        // 400000
#define BR_ (B_*R_)        // 786432
#define SCAN_E 2048
#define SCAN_BLOCKS ((BV_ + SCAN_E - 1)/SCAN_E)   // 196

// ---------------- Kernel 1: ray directions ----------------
__global__ __launch_bounds__(256) void ray_kernel(
    const float* __restrict__ pose,
    const float* __restrict__ intr,
    float* __restrict__ dout)
{
    const int blocksPerBN = HW_ / 256;  // 192
    int tid = threadIdx.x;
    int bn = blockIdx.x / blocksPerBN;
    int hw = (blockIdx.x % blocksPerBN) * 256 + tid;
    int h = hw / W_, w = hw % W_;

    __shared__ float p[12];
    __shared__ float it[4];
    if (tid < 12) p[tid] = pose[bn * 16 + tid];
    if (tid >= 12 && tid < 16) it[tid - 12] = intr[bn * 6 + (tid - 12)];
    __syncthreads();

    float fx = it[0], fy = it[1], cx = it[2], cy = it[3];
    float uu = ((float)w - cx) / fx;
    float vv = ((float)h - cy) / fy;
    float dx = p[0] * uu + p[1] * vv + p[2];
    float dy = p[4] * uu + p[5] * vv + p[6];
    float dz = p[8] * uu + p[9] * vv + p[10];
    float inv = rsqrtf(dx * dx + dy * dy + dz * dz);
    size_t o = (size_t)(bn * HW_ + hw) * 3;
    dout[o + 0] = dx * inv;
    dout[o + 1] = dy * inv;
    dout[o + 2] = dz * inv;
}

// ---------------- histogram over voxel keys ----------------
__global__ __launch_bounds__(256) void hist_kernel(
    const int* __restrict__ vox,
    const int* __restrict__ hit,
    unsigned* __restrict__ hist)
{
    int t = blockIdx.x * 256 + threadIdx.x;   // 0 .. BR_-1
    if (t >= BR_) return;
    int b = t / R_;
    if (hit[t]) atomicAdd(&hist[b * V_ + vox[t]], 1u);
}

// ---------------- 3-phase exclusive scan over hist[BV_] -> offsets (+offs2 copy) ----------------
__global__ __launch_bounds__(256) void scanA_kernel(
    const unsigned* __restrict__ hist,
    unsigned* __restrict__ blockSums)
{
    int tid = threadIdx.x;
    int base = blockIdx.x * SCAN_E + tid * 8;
    unsigned s = 0;
    #pragma unroll
    for (int j = 0; j < 8; ++j) {
        int idx = base + j;
        if (idx < BV_) s += hist[idx];
    }
    __shared__ unsigned sh[256];
    sh[tid] = s; __syncthreads();
    for (int d = 128; d > 0; d >>= 1) {
        if (tid < d) sh[tid] += sh[tid + d];
        __syncthreads();
    }
    if (tid == 0) blockSums[blockIdx.x] = sh[0];
}

__global__ __launch_bounds__(256) void scanB_kernel(
    const unsigned* __restrict__ blockSums,
    unsigned* __restrict__ blockOffsets)
{
    int tid = threadIdx.x;
    unsigned v = (tid < SCAN_BLOCKS) ? blockSums[tid] : 0u;
    __shared__ unsigned sh[256];
    sh[tid] = v; __syncthreads();
    for (int d = 1; d < 256; d <<= 1) {
        unsigned t = (tid >= d) ? sh[tid - d] : 0u;
        __syncthreads();
        sh[tid] += t;
        __syncthreads();
    }
    if (tid < SCAN_BLOCKS) blockOffsets[tid] = sh[tid] - v;   // exclusive
}

__global__ __launch_bounds__(256) void scanC_kernel(
    const unsigned* __restrict__ hist,
    const unsigned* __restrict__ blockOffsets,
    unsigned* __restrict__ offsets,
    unsigned* __restrict__ offs2)
{
    int tid = threadIdx.x;
    int base = blockIdx.x * SCAN_E + tid * 8;
    unsigned e[8];
    unsigned s = 0;
    #pragma unroll
    for (int j = 0; j < 8; ++j) {
        int idx = base + j;
        e[j] = (idx < BV_) ? hist[idx] : 0u;
        s += e[j];
    }
    __shared__ unsigned sh[256];
    sh[tid] = s; __syncthreads();
    for (int d = 1; d < 256; d <<= 1) {
        unsigned t = (tid >= d) ? sh[tid - d] : 0u;
        __syncthreads();
        sh[tid] += t;
        __syncthreads();
    }
    unsigned run = blockOffsets[blockIdx.x] + (sh[tid] - s);
    #pragma unroll
    for (int j = 0; j < 8; ++j) {
        int idx = base + j;
        if (idx < BV_) { offsets[idx] = run; offs2[idx] = run; }
        run += e[j];
    }
}

// ---------------- scatter features into sorted order (2 pixels/thread) ----------------
// Streaming 8B/lane coalesced reads of feat; dense 64B-aligned record writes.
__global__ __launch_bounds__(256) void scatterfeat_kernel(
    const float* __restrict__ feat,
    const int* __restrict__ vox,
    const int* __restrict__ hit,
    const unsigned* __restrict__ offsets,
    unsigned* __restrict__ offs2,
    float* __restrict__ gathered,
    int b0)
{
    int t = blockIdx.x * 256 + threadIdx.x;   // pixel-pair index
    int p0 = b0 * R_ + t * 2;
    int2 ht = *(const int2*)(hit + p0);
    if (!(ht.x | ht.y)) return;
    int2 vd = *(const int2*)(vox + p0);
    int b = p0 / R_;
    int r0 = p0 - b * R_;
    unsigned base = offsets[(size_t)b0 * V_];
    unsigned px = 0, py = 0;
    if (ht.x) px = atomicAdd(&offs2[b * V_ + vd.x], 1u) - base;
    if (ht.y) py = atomicAdd(&offs2[b * V_ + vd.y], 1u) - base;

    int n = r0 / HW_;
    int hw = r0 - n * HW_;
    const float* fb = feat + ((size_t)b * N_ + n) * (size_t)(C_ * HW_) + hw;
    float* gx = gathered + (size_t)px * 64;
    float* gy = gathered + (size_t)py * 64;

    #pragma unroll 1
    for (int ch = 0; ch < 4; ++ch) {
        float2 v[16];
        #pragma unroll
        for (int j = 0; j < 16; ++j)
            v[j] = *(const float2*)(fb + (size_t)(ch * 16 + j) * HW_);
        if (ht.x) {
            #pragma unroll
            for (int q = 0; q < 4; ++q) {
                float4 s;
                s.x = v[4*q].x; s.y = v[4*q+1].x; s.z = v[4*q+2].x; s.w = v[4*q+3].x;
                *(float4*)(gx + ch * 16 + q * 4) = s;
            }
        }
        if (ht.y) {
            #pragma unroll
            for (int q = 0; q < 4; ++q) {
                float4 s;
                s.x = v[4*q].y; s.y = v[4*q+1].y; s.z = v[4*q+2].y; s.w = v[4*q+3].y;
                *(float4*)(gy + ch * 16 + q * 4) = s;
            }
        }
    }
}

// ---------------- fused segment-mean + concat(conf) + GEMM + bias ----------------
// Block = 64 voxels. LDS ~29.7 KB -> 5 blocks/CU (20 waves).
// Weights K-chunked (3 x 22 rows, row 65 zero-padded). 8v x 4o register tiles.
__global__ __launch_bounds__(256) void gemm_fused_kernel(
    const float* __restrict__ gathered,
    const unsigned* __restrict__ hist,
    const unsigned* __restrict__ offsets,
    const float* __restrict__ conf,
    const float* __restrict__ wfc,
    const float* __restrict__ bfc,
    float* __restrict__ outp,
    int b0)
{
    const int VPB = 64;
    const int KC = 22;                   // K-chunk rows
    __shared__ float wl[KC][128];        // 11.3 KB
    __shared__ float voxT[66][68];       // 17.9 KB (row 64 = conf, row 65 = zero pad)
    __shared__ float bl[128];            // 0.5 KB
    int tid = threadIdx.x;
    int bv0 = b0 * V_ + blockIdx.x * VPB;
    unsigned base = offsets[(size_t)b0 * V_];

    if (tid < 128) bl[tid] = bfc[tid];
    if (tid < VPB) voxT[64][tid] = conf[bv0 + tid];
    if (tid < 68)  voxT[65][tid] = 0.0f;

    // ---- segment means: 4 waves x 16 voxels, 2 groups of 8 (MLP=8 first loads) ----
    int lane = tid & 63;
    int wv = tid >> 6;
    for (int g = 0; g < 2; ++g) {
        unsigned cn[8], st[8];
        float macc[8];
        #pragma unroll
        for (int i = 0; i < 8; ++i) {
            int bv = bv0 + wv * 16 + g * 8 + i;
            cn[i] = hist[bv];
            st[i] = offsets[bv] - base;
        }
        #pragma unroll
        for (int i = 0; i < 8; ++i)
            macc[i] = cn[i] ? gathered[(size_t)st[i] * 64 + lane] : 0.0f;
        #pragma unroll
        for (int i = 0; i < 8; ++i)
            for (unsigned k = 1; k < cn[i]; ++k)
                macc[i] += gathered[(size_t)(st[i] + k) * 64 + lane];
        #pragma unroll
        for (int i = 0; i < 8; ++i)
            voxT[lane][wv * 16 + g * 8 + i] = macc[i] / fmaxf((float)cn[i], 1.0f);
    }

    // ---- first weight chunk load (overlaps means completion) ----
    for (int i = tid; i < KC * 128; i += 256)
        wl[i >> 7][i & 127] = wfc[i];
    __syncthreads();

    int oc = tid & 31;   // output quad
    int vr = tid >> 5;   // voxel octet
    float acc[8][4];
    float4 bq = *(float4*)&bl[oc * 4];
    #pragma unroll
    for (int i = 0; i < 8; ++i) {
        acc[i][0] = bq.x; acc[i][1] = bq.y; acc[i][2] = bq.z; acc[i][3] = bq.w;
    }

    for (int h = 0; h < 3; ++h) {
        int c0 = h * KC;
        #pragma unroll
        for (int cl = 0; cl < KC; ++cl) {
            int c = c0 + cl;                 // chunk2 row 65 = zero wl x zero voxT
            float4 va = *(float4*)&voxT[c][vr * 8];
            float4 vb = *(float4*)&voxT[c][vr * 8 + 4];
            float4 w4 = *(float4*)&wl[cl][oc * 4];
            acc[0][0] += va.x * w4.x; acc[0][1] += va.x * w4.y; acc[0][2] += va.x * w4.z; acc[0][3] += va.x * w4.w;
            acc[1][0] += va.y * w4.x; acc[1][1] += va.y * w4.y; acc[1][2] += va.y * w4.z; acc[1][3] += va.y * w4.w;
            acc[2][0] += va.z * w4.x; acc[2][1] += va.z * w4.y; acc[2][2] += va.z * w4.z; acc[2][3] += va.z * w4.w;
            acc[3][0] += va.w * w4.x; acc[3][1] += va.w * w4.y; acc[3][2] += va.w * w4.z; acc[3][3] += va.w * w4.w;
            acc[4][0] += vb.x * w4.x; acc[4][1] += vb.x * w4.y; acc[4][2] += vb.x * w4.z; acc[4][3] += vb.x * w4.w;
            acc[5][0] += vb.y * w4.x; acc[5][1] += vb.y * w4.y; acc[5][2] += vb.y * w4.z; acc[5][3] += vb.y * w4.w;
            acc[6][0] += vb.z * w4.x; acc[6][1] += vb.z * w4.y; acc[6][2] += vb.z * w4.z; acc[6][3] += vb.z * w4.w;
            acc[7][0] += vb.w * w4.x; acc[7][1] += vb.w * w4.y; acc[7][2] += vb.w * w4.z; acc[7][3] += vb.w * w4.w;
        }
        if (h < 2) {
            __syncthreads();
            int c0n = (h + 1) * KC;
            int nc = (c0n + KC <= 65) ? KC : (65 - c0n);   // 22, 21
            for (int i = tid; i < KC * 128; i += 256)
                wl[i >> 7][i & 127] = (i < nc * 128) ? wfc[c0n * 128 + i] : 0.0f;
            __syncthreads();
        }
    }

    #pragma unroll
    for (int i = 0; i < 8; ++i) {
        size_t bv = (size_t)(bv0 + vr * 8 + i);
        float4 st4;
        st4.x = acc[i][0]; st4.y = acc[i][1]; st4.z = acc[i][2]; st4.w = acc[i][3];
        *(float4*)&outp[bv * OUT_ + oc * 4] = st4;
    }
}

// ---------------- Fallback atomic path (verified previously) ----------------
__global__ __launch_bounds__(256) void scatter_kernel(
    const float* __restrict__ feat,
    const int* __restrict__ vox_ids,
    const int* __restrict__ hit,
    float* __restrict__ sums,
    unsigned* __restrict__ cnts)
{
    const int PPT = 2;
    const int blocksPerBN = HW_ / (256 * PPT);  // 96
    int tid = threadIdx.x;
    int bn = blockIdx.x / blocksPerBN;
    int b = bn >> 3;
    int hw0 = (blockIdx.x % blocksPerBN) * (256 * PPT) + tid * PPT;
    int r0 = (bn & 7) * HW_ + hw0;

    int2 vid = *(const int2*)(vox_ids + (size_t)b * R_ + r0);
    int2 ht  = *(const int2*)(hit + (size_t)b * R_ + r0);
    if (!(ht.x | ht.y)) return;

    unsigned* cb = cnts + (size_t)b * V_;
    if (ht.x) atomicAdd(&cb[vid.x], 1u);
    if (ht.y) atomicAdd(&cb[vid.y], 1u);

    float* sb = sums + (size_t)b * (size_t)V_ * C_;
    float* s0 = sb + (size_t)vid.x * C_;
    float* s1 = sb + (size_t)vid.y * C_;
    const float* fb = feat + (size_t)bn * C_ * HW_ + hw0;

    #pragma unroll 8
    for (int c = 0; c < C_; ++c) {
        float2 rw = *(const float2*)(fb + (size_t)c * HW_);
        if (ht.x) unsafeAtomicAdd(s0 + c, rw.x);
        if (ht.y) unsafeAtomicAdd(s1 + c, rw.y);
    }
}

__global__ __launch_bounds__(256) void gemm_atomic_kernel(
    const float* __restrict__ sums,
    const unsigned* __restrict__ cnts,
    const float* __restrict__ conf,
    const float* __restrict__ wfc,
    const float* __restrict__ bfc,
    float* __restrict__ outp)
{
    const int VPB = 32;
    __shared__ float wl[65][128];
    __shared__ float voxT[65][36];
    __shared__ float bl[128];
    __shared__ float invc[VPB];
    int tid = threadIdx.x;
    int bv0 = blockIdx.x * VPB;

    for (int i = tid; i < 65 * 128; i += 256)
        wl[i >> 7][i & 127] = wfc[i];
    if (tid < 128) bl[tid] = bfc[tid];
    if (tid < VPB) {
        unsigned cn = cnts[bv0 + tid];
        invc[tid] = 1.0f / (float)(cn > 1u ? cn : 1u);
        voxT[64][tid] = conf[bv0 + tid];
    }
    __syncthreads();

    for (int i = tid; i < VPB * C_; i += 256) {
        int vx = i >> 6, c = i & 63;
        voxT[c][vx] = sums[(size_t)bv0 * C_ + i] * invc[vx];
    }
    __syncthreads();

    int oc = tid & 31;
    int vr = tid >> 5;
    float acc[4][4];
    float4 bq = *(float4*)&bl[oc * 4];
    #pragma unroll
    for (int i = 0; i < 4; ++i) {
        acc[i][0] = bq.x; acc[i][1] = bq.y; acc[i][2] = bq.z; acc[i][3] = bq.w;
    }

    #pragma unroll
    for (int c = 0; c < 65; ++c) {
        float4 v4 = *(float4*)&voxT[c][vr * 4];
        float4 w4 = *(float4*)&wl[c][oc * 4];
        acc[0][0] += v4.x * w4.x; acc[0][1] += v4.x * w4.y; acc[0][2] += v4.x * w4.z; acc[0][3] += v4.x * w4.w;
        acc[1][0] += v4.y * w4.x; acc[1][1] += v4.y * w4.y; acc[1][2] += v4.y * w4.z; acc[1][3] += v4.y * w4.w;
        acc[2][0] += v4.z * w4.x; acc[2][1] += v4.z * w4.y; acc[2][2] += v4.z * w4.z; acc[2][3] += v4.z * w4.w;
        acc[3][0] += v4.w * w4.x; acc[3][1] += v4.w * w4.y; acc[3][2] += v4.w * w4.z; acc[3][3] += v4.w * w4.w;
    }

    #pragma unroll
    for (int i = 0; i < 4; ++i) {
        size_t bv = (size_t)(bv0 + vr * 4 + i);
        float4 st;
        st.x = acc[i][0]; st.y = acc[i][1]; st.z = acc[i][2]; st.w = acc[i][3];
        *(float4*)&outp[bv * OUT_ + oc * 4] = st;
    }
}

extern "C" void kernel_launch(void* const* d_in, const int* in_sizes, int n_in,
                              void* d_out, int out_size, void* d_ws, size_t ws_size,
                              hipStream_t stream) {
    const float* pose = (const float*)d_in[0];
    const float* intr = (const float*)d_in[1];
    const float* feat = (const float*)d_in[2];
    // d_in[3] = depths (unused by reference)
    const float* conf = (const float*)d_in[4];
    const int* vox_ids = (const int*)d_in[5];
    const int* hit = (const int*)d_in[6];
    const float* wfc = (const float*)d_in[7];
    const float* bfc = (const float*)d_in[8];

    float* out = (float*)d_out;
    float* dray = out + (size_t)B_ * V_ * OUT_;  // d follows out

    ray_kernel<<<(B_ * N_ * HW_) / 256, 256, 0, stream>>>(pose, intr, dray);

    size_t hist_bytes = (size_t)BV_ * sizeof(unsigned);                 // 1.6 MB
    size_t gath_full  = (size_t)BR_ * C_ * sizeof(float);               // 201.3 MB
    size_t gath_batch = (size_t)R_ * C_ * sizeof(float);                // 100.7 MB
    size_t ovh = 3 * hist_bytes + 512 * sizeof(unsigned);               // hist+offsets+offs2+scan tmp
    size_t need_full  = gath_full + ovh;                                // ~206.1 MB
    size_t need_batch = gath_batch + ovh;                               // ~105.5 MB

    if (ws_size >= need_batch) {
        size_t gath_bytes = (ws_size >= need_full) ? gath_full : gath_batch;
        float* gathered = (float*)d_ws;
        unsigned* hist = (unsigned*)((char*)d_ws + gath_bytes);
        unsigned* offsets = hist + BV_;
        unsigned* offs2 = offsets + BV_;
        unsigned* blockSums = offs2 + BV_;
        unsigned* blockOffsets = blockSums + 256;

        hipMemsetAsync(hist, 0, hist_bytes, stream);
        hist_kernel<<<BR_ / 256, 256, 0, stream>>>(vox_ids, hit, hist);
        scanA_kernel<<<SCAN_BLOCKS, 256, 0, stream>>>(hist, blockSums);
        scanB_kernel<<<1, 256, 0, stream>>>(blockSums, blockOffsets);
        scanC_kernel<<<SCAN_BLOCKS, 256, 0, stream>>>(hist, blockOffsets, offsets, offs2);

        if (ws_size >= need_full) {
            // single pass over both batches
            scatterfeat_kernel<<<BR_ / 512, 256, 0, stream>>>(feat, vox_ids, hit, offsets, offs2, gathered, 0);
            gemm_fused_kernel<<<BV_ / 64, 256, 0, stream>>>(gathered, hist, offsets, conf, wfc, bfc, out, 0);
        } else {
            // per-batch passes sharing one gathered buffer (stream-serialized)
            for (int b = 0; b < B_; ++b) {
                scatterfeat_kernel<<<R_ / 512, 256, 0, stream>>>(feat, vox_ids, hit, offsets, offs2, gathered, b);
                gemm_fused_kernel<<<V_ / 64, 256, 0, stream>>>(gathered, hist, offsets, conf, wfc, bfc, out, b);
            }
        }
    } else {
        // -------- fallback: verified atomic path --------
        float* sums = (float*)d_ws;
        size_t sums_bytes = (size_t)B_ * V_ * C_ * sizeof(float);
        unsigned* cnts = (unsigned*)((char*)d_ws + sums_bytes);
        size_t cnts_bytes = (size_t)B_ * V_ * sizeof(unsigned);

        hipMemsetAsync(d_ws, 0, sums_bytes + cnts_bytes, stream);
        scatter_kernel<<<(B_ * N_ * HW_) / (256 * 2), 256, 0, stream>>>(feat, vox_ids, hit, sums, cnts);
        gemm_atomic_kernel<<<(B_ * V_) / 32, 256, 0, stream>>>(sums, cnts, conf, wfc, bfc, out);
    }
}

// Round 5
// 707.556 us; speedup vs baseline: 1.1371x; 1.1371x over previous
//
#include <hip/hip_runtime.h>
#include <hip/hip_bf16.h>

#define B_ 2
#define N_ 8
#define C_ 64
#define H_ 192
#define W_ 256
#define V_ 200000
#define OUT_ 128
#define HW_ (H_*W_)        // 49152
#define R_ (N_*HW_)        // 393216
#define BV_ (B_*V_)        // 400000
#define BR_ (B_*R_)        // 786432
#define SCAN_E 2048
#define SCAN_BLOCKS ((BV_ + SCAN_E - 1)/SCAN_E)   // 196

// ---------------- ray directions (fallback path only) ----------------
__global__ __launch_bounds__(256) void ray_kernel(
    const float* __restrict__ pose,
    const float* __restrict__ intr,
    float* __restrict__ dout)
{
    const int blocksPerBN = HW_ / 256;  // 192
    int tid = threadIdx.x;
    int bn = blockIdx.x / blocksPerBN;
    int hw = (blockIdx.x % blocksPerBN) * 256 + tid;
    int h = hw / W_, w = hw % W_;

    __shared__ float p[12];
    __shared__ float it[4];
    if (tid < 12) p[tid] = pose[bn * 16 + tid];
    if (tid >= 12 && tid < 16) it[tid - 12] = intr[bn * 6 + (tid - 12)];
    __syncthreads();

    float fx = it[0], fy = it[1], cx = it[2], cy = it[3];
    float uu = ((float)w - cx) / fx;
    float vv = ((float)h - cy) / fy;
    float dx = p[0] * uu + p[1] * vv + p[2];
    float dy = p[4] * uu + p[5] * vv + p[6];
    float dz = p[8] * uu + p[9] * vv + p[10];
    float inv = rsqrtf(dx * dx + dy * dy + dz * dz);
    size_t o = (size_t)(bn * HW_ + hw) * 3;
    dout[o + 0] = dx * inv;
    dout[o + 1] = dy * inv;
    dout[o + 2] = dz * inv;
}

// ---------------- merged ray + histogram (sorted path) ----------------
// Same BR-pixel domain: compute ray dir AND count voxel hits in one pass.
__global__ __launch_bounds__(256) void rayhist_kernel(
    const float* __restrict__ pose,
    const float* __restrict__ intr,
    const int* __restrict__ vox,
    const int* __restrict__ hit,
    float* __restrict__ dout,
    unsigned* __restrict__ hist)
{
    const int blocksPerBN = HW_ / 256;  // 192
    int tid = threadIdx.x;
    int bn = blockIdx.x / blocksPerBN;
    int hw = (blockIdx.x % blocksPerBN) * 256 + tid;
    int h = hw / W_, w = hw % W_;
    int t = blockIdx.x * 256 + tid;     // global pixel = bn*HW_ + hw

    __shared__ float p[12];
    __shared__ float it[4];
    if (tid < 12) p[tid] = pose[bn * 16 + tid];
    if (tid >= 12 && tid < 16) it[tid - 12] = intr[bn * 6 + (tid - 12)];
    __syncthreads();

    float fx = it[0], fy = it[1], cx = it[2], cy = it[3];
    float uu = ((float)w - cx) / fx;
    float vv = ((float)h - cy) / fy;
    float dx = p[0] * uu + p[1] * vv + p[2];
    float dy = p[4] * uu + p[5] * vv + p[6];
    float dz = p[8] * uu + p[9] * vv + p[10];
    float inv = rsqrtf(dx * dx + dy * dy + dz * dz);
    size_t o = (size_t)t * 3;
    dout[o + 0] = dx * inv;
    dout[o + 1] = dy * inv;
    dout[o + 2] = dz * inv;

    if (hit[t]) atomicAdd(&hist[(bn >> 3) * V_ + vox[t]], 1u);
}

// ---------------- 3-phase exclusive scan over hist[BV_] -> offsets (+offs2) ----------------
__global__ __launch_bounds__(256) void scanA_kernel(
    const unsigned* __restrict__ hist,
    unsigned* __restrict__ blockSums)
{
    int tid = threadIdx.x;
    int base = blockIdx.x * SCAN_E + tid * 8;
    unsigned s = 0;
    #pragma unroll
    for (int j = 0; j < 8; ++j) {
        int idx = base + j;
        if (idx < BV_) s += hist[idx];
    }
    __shared__ unsigned sh[256];
    sh[tid] = s; __syncthreads();
    for (int d = 128; d > 0; d >>= 1) {
        if (tid < d) sh[tid] += sh[tid + d];
        __syncthreads();
    }
    if (tid == 0) blockSums[blockIdx.x] = sh[0];
}

__global__ __launch_bounds__(256) void scanB_kernel(
    const unsigned* __restrict__ blockSums,
    unsigned* __restrict__ blockOffsets)
{
    int tid = threadIdx.x;
    unsigned v = (tid < SCAN_BLOCKS) ? blockSums[tid] : 0u;
    __shared__ unsigned sh[256];
    sh[tid] = v; __syncthreads();
    for (int d = 1; d < 256; d <<= 1) {
        unsigned t = (tid >= d) ? sh[tid - d] : 0u;
        __syncthreads();
        sh[tid] += t;
        __syncthreads();
    }
    if (tid < SCAN_BLOCKS) blockOffsets[tid] = sh[tid] - v;   // exclusive
}

__global__ __launch_bounds__(256) void scanC_kernel(
    const unsigned* __restrict__ hist,
    const unsigned* __restrict__ blockOffsets,
    unsigned* __restrict__ offsets,
    unsigned* __restrict__ offs2)
{
    int tid = threadIdx.x;
    int base = blockIdx.x * SCAN_E + tid * 8;
    unsigned e[8];
    unsigned s = 0;
    #pragma unroll
    for (int j = 0; j < 8; ++j) {
        int idx = base + j;
        e[j] = (idx < BV_) ? hist[idx] : 0u;
        s += e[j];
    }
    __shared__ unsigned sh[256];
    sh[tid] = s; __syncthreads();
    for (int d = 1; d < 256; d <<= 1) {
        unsigned t = (tid >= d) ? sh[tid - d] : 0u;
        __syncthreads();
        sh[tid] += t;
        __syncthreads();
    }
    unsigned run = blockOffsets[blockIdx.x] + (sh[tid] - s);
    #pragma unroll
    for (int j = 0; j < 8; ++j) {
        int idx = base + j;
        if (idx < BV_) { offsets[idx] = run; offs2[idx] = run; }
        run += e[j];
    }
}

// ---------------- scatter features into sorted order (4 pixels/thread) ----------------
// Streaming 16B/lane coalesced reads of feat; dense 64B-aligned record writes.
__global__ __launch_bounds__(256) void scatterfeat_kernel(
    const float* __restrict__ feat,
    const int* __restrict__ vox,
    const int* __restrict__ hit,
    const unsigned* __restrict__ offsets,
    unsigned* __restrict__ offs2,
    float* __restrict__ gathered,
    int b0)
{
    int t = blockIdx.x * 256 + threadIdx.x;   // pixel-quad index
    int p0 = b0 * R_ + t * 4;
    int4 ht = *(const int4*)(hit + p0);
    if (!(ht.x | ht.y | ht.z | ht.w)) return;
    int4 vd = *(const int4*)(vox + p0);
    int b = p0 / R_;                          // quads never straddle batches
    int r0 = p0 - b * R_;
    unsigned base = offsets[(size_t)b0 * V_];
    unsigned p_x = 0, p_y = 0, p_z = 0, p_w = 0;
    if (ht.x) p_x = atomicAdd(&offs2[b * V_ + vd.x], 1u) - base;
    if (ht.y) p_y = atomicAdd(&offs2[b * V_ + vd.y], 1u) - base;
    if (ht.z) p_z = atomicAdd(&offs2[b * V_ + vd.z], 1u) - base;
    if (ht.w) p_w = atomicAdd(&offs2[b * V_ + vd.w], 1u) - base;

    int n = r0 / HW_;
    int hw = r0 - n * HW_;                    // quad within one image row
    const float* fb = feat + ((size_t)b * N_ + n) * (size_t)(C_ * HW_) + hw;
    float* g0 = gathered + (size_t)p_x * 64;
    float* g1 = gathered + (size_t)p_y * 64;
    float* g2 = gathered + (size_t)p_z * 64;
    float* g3 = gathered + (size_t)p_w * 64;

    #pragma unroll 1
    for (int ch = 0; ch < 4; ++ch) {
        float4 v[16];
        #pragma unroll
        for (int j = 0; j < 16; ++j)
            v[j] = *(const float4*)(fb + (size_t)(ch * 16 + j) * HW_);
        if (ht.x) {
            #pragma unroll
            for (int q = 0; q < 4; ++q) {
                float4 s; s.x = v[4*q].x; s.y = v[4*q+1].x; s.z = v[4*q+2].x; s.w = v[4*q+3].x;
                *(float4*)(g0 + ch * 16 + q * 4) = s;
            }
        }
        if (ht.y) {
            #pragma unroll
            for (int q = 0; q < 4; ++q) {
                float4 s; s.x = v[4*q].y; s.y = v[4*q+1].y; s.z = v[4*q+2].y; s.w = v[4*q+3].y;
                *(float4*)(g1 + ch * 16 + q * 4) = s;
            }
        }
        if (ht.z) {
            #pragma unroll
            for (int q = 0; q < 4; ++q) {
                float4 s; s.x = v[4*q].z; s.y = v[4*q+1].z; s.z = v[4*q+2].z; s.w = v[4*q+3].z;
                *(float4*)(g2 + ch * 16 + q * 4) = s;
            }
        }
        if (ht.w) {
            #pragma unroll
            for (int q = 0; q < 4; ++q) {
                float4 s; s.x = v[4*q].w; s.y = v[4*q+1].w; s.z = v[4*q+2].w; s.w = v[4*q+3].w;
                *(float4*)(g3 + ch * 16 + q * 4) = s;
            }
        }
    }
}

// ---------------- fused segment-mean + concat(conf) + GEMM + bias ----------------
// R3 structure (VPB=32, acc[4][4], VGPR~68) + 2-chunk weights: LDS 43.5 -> 26.9 KB
// -> LDS cap 5 blocks/CU (was 3). wl chunk1 row 32 and voxT row 65 are zero pads.
__global__ __launch_bounds__(256) void gemm_fused_kernel(
    const float* __restrict__ gathered,
    const unsigned* __restrict__ hist,
    const unsigned* __restrict__ offsets,
    const float* __restrict__ conf,
    const float* __restrict__ wfc,
    const float* __restrict__ bfc,
    float* __restrict__ outp,
    int b0)
{
    const int VPB = 32;
    const int KC = 33;                   // K-chunk rows (2 chunks cover 66 = 65 + pad)
    __shared__ float wl[KC][128];        // 16.9 KB
    __shared__ float voxT[66][36];       // 9.5 KB (row 64 = conf, row 65 = zero)
    __shared__ float bl[128];            // 0.5 KB
    int tid = threadIdx.x;
    int bv0 = b0 * V_ + blockIdx.x * VPB;
    unsigned base = offsets[(size_t)b0 * V_];

    if (tid < 128) bl[tid] = bfc[tid];
    if (tid < VPB) voxT[64][tid] = conf[bv0 + tid];
    if (tid >= 128 && tid < 128 + 36) voxT[65][tid - 128] = 0.0f;

    // ---- segment means: 4 waves x 8 voxels, first loads issued together (MLP=8) ----
    int lane = tid & 63;
    int wv = tid >> 6;
    {
        unsigned cn[8], st[8];
        float macc[8];
        #pragma unroll
        for (int i = 0; i < 8; ++i) {
            int bv = bv0 + wv * 8 + i;
            cn[i] = hist[bv];
            st[i] = offsets[bv] - base;
        }
        #pragma unroll
        for (int i = 0; i < 8; ++i)
            macc[i] = cn[i] ? gathered[(size_t)st[i] * 64 + lane] : 0.0f;
        #pragma unroll
        for (int i = 0; i < 8; ++i)
            for (unsigned k = 1; k < cn[i]; ++k)
                macc[i] += gathered[(size_t)(st[i] + k) * 64 + lane];
        #pragma unroll
        for (int i = 0; i < 8; ++i)
            voxT[lane][wv * 8 + i] = macc[i] / fmaxf((float)cn[i], 1.0f);
    }

    // ---- weight chunk 0 (rows 0..32) ----
    for (int i = tid; i < KC * 128; i += 256)
        wl[i >> 7][i & 127] = wfc[i];
    __syncthreads();

    int oc = tid & 31;   // output quad
    int vr = tid >> 5;   // voxel quad
    float acc[4][4];
    float4 bq = *(float4*)&bl[oc * 4];
    #pragma unroll
    for (int i = 0; i < 4; ++i) {
        acc[i][0] = bq.x; acc[i][1] = bq.y; acc[i][2] = bq.z; acc[i][3] = bq.w;
    }

    for (int h = 0; h < 2; ++h) {
        int c0 = h * KC;
        #pragma unroll
        for (int cl = 0; cl < KC; ++cl) {
            int c = c0 + cl;             // h=1, cl=32 -> c=65: zero voxT x zero wl
            float4 v4 = *(float4*)&voxT[c][vr * 4];
            float4 w4 = *(float4*)&wl[cl][oc * 4];
            acc[0][0] += v4.x * w4.x; acc[0][1] += v4.x * w4.y; acc[0][2] += v4.x * w4.z; acc[0][3] += v4.x * w4.w;
            acc[1][0] += v4.y * w4.x; acc[1][1] += v4.y * w4.y; acc[1][2] += v4.y * w4.z; acc[1][3] += v4.y * w4.w;
            acc[2][0] += v4.z * w4.x; acc[2][1] += v4.z * w4.y; acc[2][2] += v4.z * w4.z; acc[2][3] += v4.z * w4.w;
            acc[3][0] += v4.w * w4.x; acc[3][1] += v4.w * w4.y; acc[3][2] += v4.w * w4.z; acc[3][3] += v4.w * w4.w;
        }
        if (h == 0) {
            __syncthreads();
            // chunk 1: rows 33..64 real, row index 32 zero pad
            for (int i = tid; i < KC * 128; i += 256) {
                int r = i >> 7;
                wl[r][i & 127] = (r < 32) ? wfc[(33 + r) * 128 + (i & 127)] : 0.0f;
            }
            __syncthreads();
        }
    }

    #pragma unroll
    for (int i = 0; i < 4; ++i) {
        size_t bv = (size_t)(bv0 + vr * 4 + i);
        float4 st4;
        st4.x = acc[i][0]; st4.y = acc[i][1]; st4.z = acc[i][2]; st4.w = acc[i][3];
        *(float4*)&outp[bv * OUT_ + oc * 4] = st4;
    }
}

// ---------------- Fallback atomic path (verified previously) ----------------
__global__ __launch_bounds__(256) void scatter_kernel(
    const float* __restrict__ feat,
    const int* __restrict__ vox_ids,
    const int* __restrict__ hit,
    float* __restrict__ sums,
    unsigned* __restrict__ cnts)
{
    const int PPT = 2;
    const int blocksPerBN = HW_ / (256 * PPT);  // 96
    int tid = threadIdx.x;
    int bn = blockIdx.x / blocksPerBN;
    int b = bn >> 3;
    int hw0 = (blockIdx.x % blocksPerBN) * (256 * PPT) + tid * PPT;
    int r0 = (bn & 7) * HW_ + hw0;

    int2 vid = *(const int2*)(vox_ids + (size_t)b * R_ + r0);
    int2 ht  = *(const int2*)(hit + (size_t)b * R_ + r0);
    if (!(ht.x | ht.y)) return;

    unsigned* cb = cnts + (size_t)b * V_;
    if (ht.x) atomicAdd(&cb[vid.x], 1u);
    if (ht.y) atomicAdd(&cb[vid.y], 1u);

    float* sb = sums + (size_t)b * (size_t)V_ * C_;
    float* s0 = sb + (size_t)vid.x * C_;
    float* s1 = sb + (size_t)vid.y * C_;
    const float* fb = feat + (size_t)bn * C_ * HW_ + hw0;

    #pragma unroll 8
    for (int c = 0; c < C_; ++c) {
        float2 rw = *(const float2*)(fb + (size_t)c * HW_);
        if (ht.x) unsafeAtomicAdd(s0 + c, rw.x);
        if (ht.y) unsafeAtomicAdd(s1 + c, rw.y);
    }
}

__global__ __launch_bounds__(256) void gemm_atomic_kernel(
    const float* __restrict__ sums,
    const unsigned* __restrict__ cnts,
    const float* __restrict__ conf,
    const float* __restrict__ wfc,
    const float* __restrict__ bfc,
    float* __restrict__ outp)
{
    const int VPB = 32;
    __shared__ float wl[65][128];
    __shared__ float voxT[65][36];
    __shared__ float bl[128];
    __shared__ float invc[VPB];
    int tid = threadIdx.x;
    int bv0 = blockIdx.x * VPB;

    for (int i = tid; i < 65 * 128; i += 256)
        wl[i >> 7][i & 127] = wfc[i];
    if (tid < 128) bl[tid] = bfc[tid];
    if (tid < VPB) {
        unsigned cn = cnts[bv0 + tid];
        invc[tid] = 1.0f / (float)(cn > 1u ? cn : 1u);
        voxT[64][tid] = conf[bv0 + tid];
    }
    __syncthreads();

    for (int i = tid; i < VPB * C_; i += 256) {
        int vx = i >> 6, c = i & 63;
        voxT[c][vx] = sums[(size_t)bv0 * C_ + i] * invc[vx];
    }
    __syncthreads();

    int oc = tid & 31;
    int vr = tid >> 5;
    float acc[4][4];
    float4 bq = *(float4*)&bl[oc * 4];
    #pragma unroll
    for (int i = 0; i < 4; ++i) {
        acc[i][0] = bq.x; acc[i][1] = bq.y; acc[i][2] = bq.z; acc[i][3] = bq.w;
    }

    #pragma unroll
    for (int c = 0; c < 65; ++c) {
        float4 v4 = *(float4*)&voxT[c][vr * 4];
        float4 w4 = *(float4*)&wl[c][oc * 4];
        acc[0][0] += v4.x * w4.x; acc[0][1] += v4.x * w4.y; acc[0][2] += v4.x * w4.z; acc[0][3] += v4.x * w4.w;
        acc[1][0] += v4.y * w4.x; acc[1][1] += v4.y * w4.y; acc[1][2] += v4.y * w4.z; acc[1][3] += v4.y * w4.w;
        acc[2][0] += v4.z * w4.x; acc[2][1] += v4.z * w4.y; acc[2][2] += v4.z * w4.z; acc[2][3] += v4.z * w4.w;
        acc[3][0] += v4.w * w4.x; acc[3][1] += v4.w * w4.y; acc[3][2] += v4.w * w4.z; acc[3][3] += v4.w * w4.w;
    }

    #pragma unroll
    for (int i = 0; i < 4; ++i) {
        size_t bv = (size_t)(bv0 + vr * 4 + i);
        float4 st;
        st.x = acc[i][0]; st.y = acc[i][1]; st.z = acc[i][2]; st.w = acc[i][3];
        *(float4*)&outp[bv * OUT_ + oc * 4] = st;
    }
}

extern "C" void kernel_launch(void* const* d_in, const int* in_sizes, int n_in,
                              void* d_out, int out_size, void* d_ws, size_t ws_size,
                              hipStream_t stream) {
    const float* pose = (const float*)d_in[0];
    const float* intr = (const float*)d_in[1];
    const float* feat = (const float*)d_in[2];
    // d_in[3] = depths (unused by reference)
    const float* conf = (const float*)d_in[4];
    const int* vox_ids = (const int*)d_in[5];
    const int* hit = (const int*)d_in[6];
    const float* wfc = (const float*)d_in[7];
    const float* bfc = (const float*)d_in[8];

    float* out = (float*)d_out;
    float* dray = out + (size_t)B_ * V_ * OUT_;  // d follows out

    size_t hist_bytes = (size_t)BV_ * sizeof(unsigned);                 // 1.6 MB
    size_t gath_full  = (size_t)BR_ * C_ * sizeof(float);               // 201.3 MB
    size_t gath_batch = (size_t)R_ * C_ * sizeof(float);                // 100.7 MB
    size_t ovh = 3 * hist_bytes + 512 * sizeof(unsigned);               // hist+offsets+offs2+scan tmp
    size_t need_full  = gath_full + ovh;                                // ~206.1 MB
    size_t need_batch = gath_batch + ovh;                               // ~105.5 MB

    if (ws_size >= need_batch) {
        size_t gath_bytes = (ws_size >= need_full) ? gath_full : gath_batch;
        float* gathered = (float*)d_ws;
        unsigned* hist = (unsigned*)((char*)d_ws + gath_bytes);
        unsigned* offsets = hist + BV_;
        unsigned* offs2 = offsets + BV_;
        unsigned* blockSums = offs2 + BV_;
        unsigned* blockOffsets = blockSums + 256;

        hipMemsetAsync(hist, 0, hist_bytes, stream);
        rayhist_kernel<<<BR_ / 256, 256, 0, stream>>>(pose, intr, vox_ids, hit, dray, hist);
        scanA_kernel<<<SCAN_BLOCKS, 256, 0, stream>>>(hist, blockSums);
        scanB_kernel<<<1, 256, 0, stream>>>(blockSums, blockOffsets);
        scanC_kernel<<<SCAN_BLOCKS, 256, 0, stream>>>(hist, blockOffsets, offsets, offs2);

        if (ws_size >= need_full) {
            // single pass over both batches
            scatterfeat_kernel<<<BR_ / 1024, 256, 0, stream>>>(feat, vox_ids, hit, offsets, offs2, gathered, 0);
            gemm_fused_kernel<<<BV_ / 32, 256, 0, stream>>>(gathered, hist, offsets, conf, wfc, bfc, out, 0);
        } else {
            // per-batch passes sharing one gathered buffer (stream-serialized)
            for (int b = 0; b < B_; ++b) {
                scatterfeat_kernel<<<R_ / 1024, 256, 0, stream>>>(feat, vox_ids, hit, offsets, offs2, gathered, b);
                gemm_fused_kernel<<<V_ / 32, 256, 0, stream>>>(gathered, hist, offsets, conf, wfc, bfc, out, b);
            }
        }
    } else {
        // -------- fallback: verified atomic path --------
        float* sums = (float*)d_ws;
        size_t sums_bytes = (size_t)B_ * V_ * C_ * sizeof(float);
        unsigned* cnts = (unsigned*)((char*)d_ws + sums_bytes);
        size_t cnts_bytes = (size_t)B_ * V_ * sizeof(unsigned);

        ray_kernel<<<(B_ * N_ * HW_) / 256, 256, 0, stream>>>(pose, intr, dray);
        hipMemsetAsync(d_ws, 0, sums_bytes + cnts_bytes, stream);
        scatter_kernel<<<(B_ * N_ * HW_) / (256 * 2), 256, 0, stream>>>(feat, vox_ids, hit, sums, cnts);
        gemm_atomic_kernel<<<(B_ * V_) / 32, 256, 0, stream>>>(sums, cnts, conf, wfc, bfc, out);
    }
}